// Round 8
// baseline (210.596 us; speedup 1.0000x reference)
//
#include <hip/hip_runtime.h>

// ---- problem constants ----
constexpr int N    = 20000;
constexpr int T    = 12;
constexpr int C    = 256;
constexpr int HIDN = 128;
constexpr int OUTD = 12;
constexpr int ER   = 30000;
constexpr int NFT  = 48;               // F*T floats per node
constexpr int EDGE_TOT = 5 * ER;       // 150000
constexpr int CAP      = 32;           // combined bucket capacity (mean 7.5 edges/node)
constexpr int EB       = 586;          // edge blocks = ceil(150000/256)

// workspace layout (4-byte units); deg+cnt+Mv contiguous -> ONE memset
constexpr int WS_DEG    = 0;          // [100000] float
constexpr int WS_CNT    = 100000;     // [20000] int
constexpr int WS_MV     = 120000;     // [10*C + T] float (atomically accumulated)
constexpr int WS_ZEND   = 122576;     // memset end (floats)
constexpr int WS_WP     = 122576;     // 32768 bf16 = 16384 floats (W1 B-frags)
constexpr int WS_W2T    = 138960;     // [OUTD*HIDN] float
constexpr int WS_BUCKET = 140496;     // [N*CAP] int2 (src, coef-bits), 8B-aligned

constexpr float LOG2E = 1.4426950408889634f;

typedef __attribute__((ext_vector_type(8))) short short8;
typedef __attribute__((ext_vector_type(4))) float floatx4;

#if __has_builtin(__builtin_amdgcn_exp2f)
#define EXP2(x) __builtin_amdgcn_exp2f(x)
#else
#define EXP2(x) exp2f(x)
#endif

__device__ __forceinline__ short f2bf(float f) {   // RNE float->bf16
  unsigned u = __float_as_uint(f);
  u = u + 0x7fffu + ((u >> 16) & 1u);
  return (short)(u >> 16);
}

__device__ __forceinline__ void pick_region(
    int r,
    const int* e0, const int* e1, const int* e2, const int* e3, const int* e4,
    const float* a0, const float* a1, const float* a2, const float* a3, const float* a4,
    const int*& ei, const float*& ea) {
  switch (r) {
    case 0: ei = e0; ea = a0; break;
    case 1: ei = e1; ea = a1; break;
    case 2: ei = e2; ea = a2; break;
    case 3: ei = e3; ea = a3; break;
    default: ei = e4; ea = a4; break;
  }
}

// 1) prep + degree pass (independent work split by blockIdx):
//    b<16      : weight-collapse PARTIALS -> atomicAdd Mv (z pre-scaled log2e, h 2*log2e)
//    b==16     : softmax(att)
//    17<=b<152 : W1 -> bf16 MFMA-B frags; W2 -> W2t
//    b>=152    : deg[rn] += w
__global__ void k_prep_deg(
    const float* __restrict__ Wc_z, const float* __restrict__ bc_z,
    const float* __restrict__ Wl_z, const float* __restrict__ bl_z,
    const float* __restrict__ Wc_h, const float* __restrict__ bc_h,
    const float* __restrict__ Wl_h, const float* __restrict__ bl_h,
    const float* __restrict__ att, const float* __restrict__ W1,
    const float* __restrict__ W2,
    const int* __restrict__ e0, const int* __restrict__ e1,
    const int* __restrict__ e2, const int* __restrict__ e3,
    const int* __restrict__ e4,
    const float* __restrict__ a0, const float* __restrict__ a1,
    const float* __restrict__ a2, const float* __restrict__ a3,
    const float* __restrict__ a4,
    float* __restrict__ Mv, short* __restrict__ Wp, float* __restrict__ W2t,
    float* __restrict__ deg) {
  int b = blockIdx.x, tid = threadIdx.x;
  if (b < 16) {
    int g  = b >> 3;
    int ch = b & 7;
    int k  = tid;
    const float* Wc = g ? Wc_h : Wc_z;
    const float* bc = g ? bc_h : bc_z;
    const float* Wl = g ? Wl_h : Wl_z;
    const float* bl = g ? bl_h : bl_z;
    float scale = g ? 2.0f * LOG2E : LOG2E;
    float m0 = 0.f, m1 = 0.f, m2 = 0.f, m3 = 0.f;
    float v = (ch == 0) ? bl[k] : 0.0f;
    int c0 = ch * 32;
    for (int c = c0; c < c0 + 32; c++) {
      float wl = Wl[c * C + k];
      m0 = fmaf(Wc[0 * C + c], wl, m0);
      m1 = fmaf(Wc[1 * C + c], wl, m1);
      m2 = fmaf(Wc[2 * C + c], wl, m2);
      m3 = fmaf(Wc[3 * C + c], wl, m3);
      v  = fmaf(bc[c], wl, v);
    }
    float* o = Mv + g * (5 * C);
    atomicAdd(&o[0 * C + k], scale * m0);
    atomicAdd(&o[1 * C + k], scale * m1);
    atomicAdd(&o[2 * C + k], scale * m2);
    atomicAdd(&o[3 * C + k], scale * m3);
    atomicAdd(&o[4 * C + k], scale * v);
    return;
  }
  if (b == 16) {
    if (tid < T) {
      float amax = -3.0e38f;
      for (int t = 0; t < T; t++) amax = fmaxf(amax, att[t]);
      float s = 0.f;
      for (int t = 0; t < T; t++) s += __expf(att[t] - amax);
      Mv[10 * C + tid] = __expf(att[tid] - amax) / s;
    }
    return;
  }
  if (b < 152) {
    int idx = (b - 17) * 256 + tid;
    if (idx < 32768) {
      int j    = idx & 7;
      int lane = (idx >> 3) & 63;
      int ch   = (idx >> 9) & 7;
      int kt   = idx >> 12;
      int cin  = ch * 32 + (lane >> 4) * 8 + j;   // K index
      int kout = kt * 16 + (lane & 15);           // N index
      Wp[idx] = f2bf(W1[cin * HIDN + kout]);
    } else if (idx < 32768 + 1536) {
      int r = idx - 32768;
      int o = r >> 7, k = r & 127;
      W2t[r] = W2[k * OUTD + o];
    }
    return;
  }
  int i = (b - 152) * 256 + tid;
  if (i >= EDGE_TOT) return;
  int r = i / ER;
  int e = i - r * ER;
  const int* ei; const float* ea;
  pick_region(r, e0, e1, e2, e3, e4, a0, a1, a2, a3, a4, ei, ea);
  atomicAdd(&deg[r * N + ei[ER + e]], ea[e]);
}

// 2) fill pass (deg final): combined per-node bucket gets (src, coef)
__global__ void k_fill(const int* __restrict__ e0, const int* __restrict__ e1,
                       const int* __restrict__ e2, const int* __restrict__ e3,
                       const int* __restrict__ e4,
                       const float* __restrict__ a0, const float* __restrict__ a1,
                       const float* __restrict__ a2, const float* __restrict__ a3,
                       const float* __restrict__ a4,
                       const float* __restrict__ deg, int* __restrict__ cnt,
                       int2* __restrict__ bucket) {
  int i = blockIdx.x * blockDim.x + threadIdx.x;
  if (i >= EDGE_TOT) return;
  int r = i / ER;
  int e = i - r * ER;
  const int* ei; const float* ea;
  pick_region(r, e0, e1, e2, e3, e4, a0, a1, a2, a3, a4, ei, ea);
  int src = ei[e];
  int dst = ei[ER + e];
  float cf = rsqrtf(deg[r * N + src] + 1.0f) * ea[e] * rsqrtf(deg[r * N + dst] + 1.0f);
  int slot = atomicAdd(&cnt[dst], 1);
  if (slot < CAP) bucket[dst * CAP + slot] = make_int2(src, __float_as_int(cf));
}

// 3) fused gather + gates + attention pooling.  ONE WAVE PER NODE (20000 waves),
//    no LDS, no barriers.  Lane=q gathers feature q into a register; compile-time
//    __shfl broadcasts (v_readlane) feed the gate math where lane owns 4 channels.
__global__ __launch_bounds__(256) void k_gather_gates(
    const float* __restrict__ x, const float* __restrict__ deg,
    const int* __restrict__ cnt, const int2* __restrict__ bucket,
    const float* __restrict__ Mv, float* __restrict__ h_out) {
  int wave = threadIdx.x >> 6, lane = threadIdx.x & 63;
  int n = blockIdx.x * 4 + wave;

  // ---- gather phase: lane = feature q (48/64 active) ----
  int q = lane < NFT ? lane : NFT - 1;
  float s = 0.f;
#pragma unroll
  for (int r = 0; r < 5; r++) s += 1.0f / (deg[r * N + n] + 1.0f);
  float facc = s * x[n * NFT + q];
  int cv = cnt[n];
  if (cv > CAP) cv = CAP;
  const int2* bk = bucket + n * CAP;
  for (int j = 0; j < cv; j++) {
    int2 m = bk[j];                      // (src, coef) wave-uniform
    facc = fmaf(__int_as_float(m.y), x[m.x * NFT + q], facc);
  }

  // ---- gate constants: lane owns channels c0..c0+3 ----
  int c0 = lane << 2;
  const float* Mz = Mv;               // pre-scaled by log2e
  const float* Mh = Mv + 5 * C;       // pre-scaled by 2*log2e
  float mz[4][4], mh[4][4], vz[4], vh[4];
#pragma unroll
  for (int f = 0; f < 4; f++) {
    float4 t1 = *(const float4*)(Mz + f * C + c0);
    mz[f][0] = t1.x; mz[f][1] = t1.y; mz[f][2] = t1.z; mz[f][3] = t1.w;
    float4 t2 = *(const float4*)(Mh + f * C + c0);
    mh[f][0] = t2.x; mh[f][1] = t2.y; mh[f][2] = t2.z; mh[f][3] = t2.w;
  }
  {
    float4 t1 = *(const float4*)(Mz + 4 * C + c0);
    vz[0] = t1.x; vz[1] = t1.y; vz[2] = t1.z; vz[3] = t1.w;
    float4 t2 = *(const float4*)(Mh + 4 * C + c0);
    vh[0] = t2.x; vh[1] = t2.y; vh[2] = t2.z; vh[3] = t2.w;
  }

  // ---- gates + temporal pooling; x_f(t) via compile-time readlane ----
  float acc[4] = {0.f, 0.f, 0.f, 0.f};
#pragma unroll
  for (int t = 0; t < T; t++) {
    float p  = Mv[10 * C + t];          // scalar load, L1-broadcast
    float x0 = __shfl(facc, t);
    float x1 = __shfl(facc, T + t);
    float x2 = __shfl(facc, 2 * T + t);
    float x3 = __shfl(facc, 3 * T + t);
#pragma unroll
    for (int j = 0; j < 4; j++) {
      float az = fmaf(mz[0][j], x0, fmaf(mz[1][j], x1, fmaf(mz[2][j], x2, fmaf(mz[3][j], x3, vz[j]))));
      float ah = fmaf(mh[0][j], x0, fmaf(mh[1][j], x1, fmaf(mh[2][j], x2, fmaf(mh[3][j], x3, vh[j]))));
      float e1 = EXP2(az);                        // e^{az_true}
      float e2 = EXP2(ah);                        // e^{2*ah_true}
      float num = e2 - 1.0f;                      // (1-Z)*tanh = num/den
      float den = (1.0f + e1) * (1.0f + e2);
      float rD  = __builtin_amdgcn_rcpf(den);
      acc[j] = fmaf(p * num, rD, acc[j]);
    }
  }
  float4 o = {acc[0], acc[1], acc[2], acc[3]};
  *(float4*)(h_out + n * C + c0) = o;   // required fp32 output, coalesced
}

// 4) MLP via bf16 MFMA.  1250 blocks x 16 nodes; stage relu(h)->bf16 in LDS,
//    16 MFMAs/wave layer-1, tiny layer-2.
__global__ __launch_bounds__(256) void k_mlp16(
    const float* __restrict__ h_in, const short* __restrict__ Wp,
    const float* __restrict__ b1, const float* __restrict__ W2t,
    const float* __restrict__ b2, float* __restrict__ y_out) {
  __shared__ short hs[16][264];       // bf16 relu(h), pad 256->264
  __shared__ float y1s[16][132];      // fp32 layer-1 out, pad 128->132
  int tid = threadIdx.x;
  int wave = tid >> 6, lane = tid & 63;
  int quad = lane >> 4, col = lane & 15;
  int n0 = blockIdx.x * 16;
  int c0 = lane << 2;

  // stage: wave w loads nodes w*4..w*4+3 (float4/lane, coalesced)
#pragma unroll
  for (int nl = 0; nl < 4; nl++) {
    int rl = wave * 4 + nl;
    float4 hv = *(const float4*)(h_in + (n0 + rl) * C + c0);
    unsigned lo = (unsigned short)f2bf(fmaxf(hv.x, 0.f)) |
                  ((unsigned)(unsigned short)f2bf(fmaxf(hv.y, 0.f)) << 16);
    unsigned hi = (unsigned short)f2bf(fmaxf(hv.z, 0.f)) |
                  ((unsigned)(unsigned short)f2bf(fmaxf(hv.w, 0.f)) << 16);
    *(int2*)&hs[rl][c0] = make_int2((int)lo, (int)hi);
  }
  __syncthreads();

  // layer 1: 16 MFMAs per wave (kt = wave*2, wave*2+1)
  floatx4 acc2[2];
  acc2[0] = {0.f, 0.f, 0.f, 0.f};
  acc2[1] = {0.f, 0.f, 0.f, 0.f};
#pragma unroll
  for (int ch = 0; ch < 8; ch++) {
    short8 a = *(const short8*)&hs[col][ch * 32 + quad * 8];
#pragma unroll
    for (int kk = 0; kk < 2; kk++) {
      short8 b = ((const short8*)Wp)[((wave * 2 + kk) * 8 + ch) * 64 + lane];
      acc2[kk] = __builtin_amdgcn_mfma_f32_16x16x32_bf16(a, b, acc2[kk], 0, 0, 0);
    }
  }
#pragma unroll
  for (int kk = 0; kk < 2; kk++) {
    int kt = wave * 2 + kk;
    float bias = b1[kt * 16 + col];
#pragma unroll
    for (int r = 0; r < 4; r++)
      y1s[quad * 4 + r][kt * 16 + col] = fmaxf(acc2[kk][r] + bias, 0.f);
  }
  __syncthreads();

  // layer 2: 16 nodes x 12 outputs = 192 threads
  if (tid < 16 * OUTD) {
    int nl = tid / OUTD, o = tid - nl * OUTD;
    float sacc = b2[o];
    const float* yr = &y1s[nl][0];
    const float* wr = W2t + o * HIDN;
#pragma unroll 8
    for (int k4 = 0; k4 < 32; k4++) {
      float4 yv = *(const float4*)(yr + 4 * k4);
      float4 wv = *(const float4*)(wr + 4 * k4);
      sacc = fmaf(yv.x, wv.x, fmaf(yv.y, wv.y, fmaf(yv.z, wv.z, fmaf(yv.w, wv.w, sacc))));
    }
    y_out[(n0 + nl) * OUTD + o] = sacc;
  }
}

extern "C" void kernel_launch(void* const* d_in, const int* in_sizes, int n_in,
                              void* d_out, int out_size, void* d_ws, size_t ws_size,
                              hipStream_t stream) {
  const float* x   = (const float*)d_in[0];
  // d_in[1] full-graph edge_index: provably unused
  const int* eIA = (const int*)d_in[2];
  const int* eKS = (const int*)d_in[3];
  const int* eKY = (const int*)d_in[4];
  const int* eOH = (const int*)d_in[5];
  const int* eWI = (const int*)d_in[6];
  const float* aIA = (const float*)d_in[7];
  const float* aKS = (const float*)d_in[8];
  const float* aKY = (const float*)d_in[9];
  const float* aOH = (const float*)d_in[10];
  const float* aWI = (const float*)d_in[11];
  const float* Wc_z = (const float*)d_in[12];
  const float* bc_z = (const float*)d_in[13];
  const float* Wl_z = (const float*)d_in[14];
  const float* bl_z = (const float*)d_in[15];
  // r-gate params (16..19) cannot influence the output (H=0)
  const float* Wc_h = (const float*)d_in[20];
  const float* bc_h = (const float*)d_in[21];
  const float* Wl_h = (const float*)d_in[22];
  const float* bl_h = (const float*)d_in[23];
  const float* att  = (const float*)d_in[24];
  const float* W1   = (const float*)d_in[25];
  const float* b1   = (const float*)d_in[26];
  const float* W2   = (const float*)d_in[27];
  const float* b2   = (const float*)d_in[28];

  float* ws     = (float*)d_ws;
  float* deg    = ws + WS_DEG;
  int*   cnt    = (int*)(ws + WS_CNT);
  float* Mv     = ws + WS_MV;
  short* Wp     = (short*)(ws + WS_WP);
  float* W2t    = ws + WS_W2T;
  int2*  bucket = (int2*)(ws + WS_BUCKET);

  float* y_out = (float*)d_out;            // [N,12]
  float* h_out = y_out + N * OUTD;         // [N,256]

  hipMemsetAsync(deg, 0, WS_ZEND * sizeof(float), stream);  // deg + cnt + Mv

  k_prep_deg<<<152 + EB, 256, 0, stream>>>(Wc_z, bc_z, Wl_z, bl_z,
                                           Wc_h, bc_h, Wl_h, bl_h,
                                           att, W1, W2,
                                           eIA, eKS, eKY, eOH, eWI,
                                           aIA, aKS, aKY, aOH, aWI,
                                           Mv, Wp, W2t, deg);
  k_fill<<<EB, 256, 0, stream>>>(eIA, eKS, eKY, eOH, eWI,
                                 aIA, aKS, aKY, aOH, aWI,
                                 deg, cnt, bucket);
  k_gather_gates<<<N / 4, 256, 0, stream>>>(x, deg, cnt, bucket, Mv, h_out);
  k_mlp16<<<N / 16, 256, 0, stream>>>(h_out, Wp, b1, W2t, b2, y_out);
}